// Round 14
// baseline (379.793 us; speedup 1.0000x reference)
//
#include <hip/hip_runtime.h>

typedef __attribute__((ext_vector_type(8))) short bf16x8;
typedef __attribute__((ext_vector_type(4))) float f32x4;
typedef __attribute__((ext_vector_type(2))) float f32x2;
typedef __attribute__((ext_vector_type(4))) unsigned int u32x4;

#define SDIM 2048
#define DDIM 64
#define NBH  32
#define KBLK 128

__device__ __forceinline__ unsigned short f2bf(float f) {
    union { float f; unsigned int u; } x;
    x.f = f;
    unsigned int u = x.u;
    u += 0x7FFFu + ((u >> 16) & 1u);  // round-to-nearest-even
    return (unsigned short)(u >> 16);
}

__device__ __forceinline__ unsigned int packbf(float a, float b) {
    return (unsigned int)f2bf(a) | ((unsigned int)f2bf(b) << 16);
}

__device__ __forceinline__ float asf(unsigned int u) {
    union { unsigned int u; float f; } x; x.u = u; return x.f;
}

// transpose [bh][R][C] f32 -> [bh][C][R] bf16(ushort), 64x64 tiles via LDS
__global__ __launch_bounds__(256) void transpose_cvt(
    const float* __restrict__ in, unsigned short* __restrict__ out,
    int R, int C)
{
    __shared__ float tile[64][65];
    const int bh = blockIdx.z;
    const int ct = blockIdx.x * 64;
    const int rt = blockIdx.y * 64;
    const float* src = in + (size_t)bh * R * C;
    unsigned short* dst = out + (size_t)bh * R * C;
    const int r = threadIdx.x >> 2;   // 0..63
    const int p = threadIdx.x & 3;    // 0..3
    const float* sp = src + (size_t)(rt + r) * C + ct + p * 16;
#pragma unroll
    for (int j = 0; j < 4; ++j) {
        f32x4 a = *(const f32x4*)(sp + j * 4);
        tile[r][p*16 + j*4 + 0] = a.x;
        tile[r][p*16 + j*4 + 1] = a.y;
        tile[r][p*16 + j*4 + 2] = a.z;
        tile[r][p*16 + j*4 + 3] = a.w;
    }
    __syncthreads();
    u32x4 w0, w1;
    w0.x = packbf(tile[p*16+ 0][r], tile[p*16+ 1][r]);
    w0.y = packbf(tile[p*16+ 2][r], tile[p*16+ 3][r]);
    w0.z = packbf(tile[p*16+ 4][r], tile[p*16+ 5][r]);
    w0.w = packbf(tile[p*16+ 6][r], tile[p*16+ 7][r]);
    w1.x = packbf(tile[p*16+ 8][r], tile[p*16+ 9][r]);
    w1.y = packbf(tile[p*16+10][r], tile[p*16+11][r]);
    w1.z = packbf(tile[p*16+12][r], tile[p*16+13][r]);
    w1.w = packbf(tile[p*16+14][r], tile[p*16+15][r]);
    unsigned short* dp = dst + (size_t)(ct + r) * R + rt + p * 16;
    *(u32x4*)dp = w0;
    *(u32x4*)(dp + 8) = w1;
}

// Fused attention, no-max softmax, KBLK=128 for DRAM page locality:
// per iteration each scores/prev row moves 512B CONTIGUOUS (4 back-to-back
// f32x4 per row) instead of 256B -> ~2x HBM row-buffer efficiency.
// K tile (16KB) single-buffered in LDS (XOR-swizzled), 2 barriers/iter:
// QK^T -> barrier -> commit next K -> barrier -> softmax/PV (off ksmem).
// S exchange: four 32-col intra-wave passes through [64][36]. PV in two
// 64-col halves (bounds VGPR). 16 iterations, all 1024 blocks resident.
__global__ __launch_bounds__(256, 4) void attn_fused(
    const float* __restrict__ q, const float* __restrict__ prev,
    const unsigned short* __restrict__ kT, const unsigned short* __restrict__ vT,
    float* __restrict__ out, float* __restrict__ scores)
{
    const int bh   = blockIdx.y;
    const int qt   = blockIdx.x;          // 64-row Q tile index
    const int tid  = threadIdx.x;
    const int wave = tid >> 6;
    const int lane = tid & 63;
    const int ln   = lane & 15;           // 0..15
    const int lg   = lane >> 4;           // 0..3

    __shared__ float s_lds[64][36];              // S/P/O exchange (two-pass)
    __shared__ unsigned short ksmem[KBLK * 64];  // K tile, 16KB, swizzled

    // ---- Q fragments (A operand: row = ln, k(d) = kc*32 + lg*8 + j) ----
    const int qrow_frag = qt * 64 + wave * 16 + ln;
    bf16x8 qf[2];
    {
        const float* qp = q + ((size_t)bh * SDIM + qrow_frag) * DDIM + lg * 8;
#pragma unroll
        for (int kc = 0; kc < 2; ++kc) {
            f32x4 a = *(const f32x4*)(qp + kc * 32);
            f32x4 b = *(const f32x4*)(qp + kc * 32 + 4);
            bf16x8 f;
            f[0] = (short)f2bf(a.x); f[1] = (short)f2bf(a.y);
            f[2] = (short)f2bf(a.z); f[3] = (short)f2bf(a.w);
            f[4] = (short)f2bf(b.x); f[5] = (short)f2bf(b.y);
            f[6] = (short)f2bf(b.z); f[7] = (short)f2bf(b.w);
            qf[kc] = f;
        }
    }

    const unsigned short* kbh   = kT + (size_t)bh * SDIM * DDIM;
    const unsigned short* vbase = vT + ((size_t)bh * DDIM + ln) * SDIM + lg * 8;

    // ---- row-layout identity: 8 lanes per row, 2 row groups ----
    const int rsub = lane >> 3;           // 0..7
    const int cq   = lane & 7;            // col octet: floats cq*4..cq*4+3
    const int rl0  = wave * 16 + rsub;    // block-local rows
    const int rl1  = rl0 + 8;
    const size_t grow0 = ((size_t)bh * SDIM + qt * 64 + rl0) * SDIM + cq * 4;
    const size_t grow1 = ((size_t)bh * SDIM + qt * 64 + rl1) * SDIM + cq * 4;
    const float* prow0 = prev + grow0;
    const float* prow1 = prev + grow1;
    float* srow0 = scores + grow0;
    float* srow1 = scores + grow1;

    f32x4 oacc[4] = {};
    float l0 = 0.0f, l1 = 0.0f;

    // ---- prologue: stage K tile 0 (1024 x 16B chunks, 4 per thread) ----
#pragma unroll
    for (int j = 0; j < 4; ++j) {
        const int c = tid + 256 * j;
        u32x4 kg = *(const u32x4*)(kbh + c * 8);
        *(u32x4*)&ksmem[(c ^ ((c >> 3) & 7)) * 8] = kg;
    }
    __syncthreads();

    for (int tt = 0; tt < SDIM / KBLK; ++tt) {
        const int t0 = tt * KBLK;
        const bool more = tt < (SDIM / KBLK - 1);

        // ---- A: issue next K tile's loads ----
        u32x4 kg0, kg1, kg2, kg3;
        if (more) {
            const unsigned short* ktn = kbh + (size_t)(t0 + KBLK) * DDIM;
            kg0 = *(const u32x4*)(ktn + (tid + 0) * 8);
            kg1 = *(const u32x4*)(ktn + (tid + 256) * 8);
            kg2 = *(const u32x4*)(ktn + (tid + 512) * 8);
            kg3 = *(const u32x4*)(ktn + (tid + 768) * 8);
        }
        // ---- B: prev half-0 (cols t0 + cq*4 + {0,32}) ----
        f32x4 pf00 = __builtin_nontemporal_load((const f32x4*)(prow0 + t0));
        f32x4 pf01 = __builtin_nontemporal_load((const f32x4*)(prow0 + t0 + 32));
        f32x4 pf10 = __builtin_nontemporal_load((const f32x4*)(prow1 + t0));
        f32x4 pf11 = __builtin_nontemporal_load((const f32x4*)(prow1 + t0 + 32));

        // ---- C: S = Q @ K^T (8 col-blocks) ----
        f32x4 sacc[8] = {};
        __builtin_amdgcn_s_setprio(1);
#pragma unroll
        for (int nc = 0; nc < 8; ++nc) {
            const int trow = nc * 16 + ln;
            const int sw = trow & 7;
#pragma unroll
            for (int kc = 0; kc < 2; ++kc) {
                bf16x8 bf = *(const bf16x8*)&ksmem[trow * 64 + ((kc * 4 + lg) ^ sw) * 8];
                sacc[nc] = __builtin_amdgcn_mfma_f32_16x16x32_bf16(qf[kc], bf, sacc[nc], 0, 0, 0);
            }
        }
        __builtin_amdgcn_s_setprio(0);

        // ---- D: barrier (all waves done reading ksmem) ----
        __syncthreads();
        // ---- E: commit next K tile ----
        if (more) {
            const int c0 = tid;
            const int c1 = tid + 256;
            const int c2 = tid + 512;
            const int c3 = tid + 768;
            *(u32x4*)&ksmem[(c0 ^ ((c0 >> 3) & 7)) * 8] = kg0;
            *(u32x4*)&ksmem[(c1 ^ ((c1 >> 3) & 7)) * 8] = kg1;
            *(u32x4*)&ksmem[(c2 ^ ((c2 >> 3) & 7)) * 8] = kg2;
            *(u32x4*)&ksmem[(c3 ^ ((c3 >> 3) & 7)) * 8] = kg3;
        }
        // ---- F: barrier (ksmem writes visible; next QK^T is after PV) ----
        __syncthreads();

        // ---- G: prev half-1 + V half-0 issue ----
        f32x4 pf02 = __builtin_nontemporal_load((const f32x4*)(prow0 + t0 + 64));
        f32x4 pf03 = __builtin_nontemporal_load((const f32x4*)(prow0 + t0 + 96));
        f32x4 pf12 = __builtin_nontemporal_load((const f32x4*)(prow1 + t0 + 64));
        f32x4 pf13 = __builtin_nontemporal_load((const f32x4*)(prow1 + t0 + 96));
        bf16x8 vf[8];
#pragma unroll
        for (int nc = 0; nc < 4; ++nc)
#pragma unroll
            for (int kc = 0; kc < 2; ++kc)
                vf[nc * 2 + kc] = *(const bf16x8*)(vbase + (size_t)nc * 16 * SDIM + (t0 + kc * 32));

        // ---- H: S exchange, four 32-col intra-wave passes ----
        f32x4 sA0, sA1, sA2, sA3, sB0, sB1, sB2, sB3;
#pragma unroll
        for (int r = 0; r < 4; ++r) {
            s_lds[wave * 16 + lg * 4 + r][ln]      = sacc[0][r];
            s_lds[wave * 16 + lg * 4 + r][16 + ln] = sacc[1][r];
        }
        sA0 = *(const f32x4*)&s_lds[rl0][cq * 4];
        sB0 = *(const f32x4*)&s_lds[rl1][cq * 4];
#pragma unroll
        for (int r = 0; r < 4; ++r) {
            s_lds[wave * 16 + lg * 4 + r][ln]      = sacc[2][r];
            s_lds[wave * 16 + lg * 4 + r][16 + ln] = sacc[3][r];
        }
        sA1 = *(const f32x4*)&s_lds[rl0][cq * 4];
        sB1 = *(const f32x4*)&s_lds[rl1][cq * 4];
#pragma unroll
        for (int r = 0; r < 4; ++r) {
            s_lds[wave * 16 + lg * 4 + r][ln]      = sacc[4][r];
            s_lds[wave * 16 + lg * 4 + r][16 + ln] = sacc[5][r];
        }
        sA2 = *(const f32x4*)&s_lds[rl0][cq * 4];
        sB2 = *(const f32x4*)&s_lds[rl1][cq * 4];
#pragma unroll
        for (int r = 0; r < 4; ++r) {
            s_lds[wave * 16 + lg * 4 + r][ln]      = sacc[6][r];
            s_lds[wave * 16 + lg * 4 + r][16 + ln] = sacc[7][r];
        }
        sA3 = *(const f32x4*)&s_lds[rl0][cq * 4];
        sB3 = *(const f32x4*)&s_lds[rl1][cq * 4];

        // ---- I: scale + prev; 512B-contiguous nt stores per row; exp ----
        sA0 = sA0 * 0.125f + pf00;
        sA1 = sA1 * 0.125f + pf01;
        sA2 = sA2 * 0.125f + pf02;
        sA3 = sA3 * 0.125f + pf03;
        sB0 = sB0 * 0.125f + pf10;
        sB1 = sB1 * 0.125f + pf11;
        sB2 = sB2 * 0.125f + pf12;
        sB3 = sB3 * 0.125f + pf13;
        __builtin_nontemporal_store(sA0, (f32x4*)(srow0 + t0));
        __builtin_nontemporal_store(sA1, (f32x4*)(srow0 + t0 + 32));
        __builtin_nontemporal_store(sA2, (f32x4*)(srow0 + t0 + 64));
        __builtin_nontemporal_store(sA3, (f32x4*)(srow0 + t0 + 96));
        __builtin_nontemporal_store(sB0, (f32x4*)(srow1 + t0));
        __builtin_nontemporal_store(sB1, (f32x4*)(srow1 + t0 + 32));
        __builtin_nontemporal_store(sB2, (f32x4*)(srow1 + t0 + 64));
        __builtin_nontemporal_store(sB3, (f32x4*)(srow1 + t0 + 96));

        f32x4 pA0, pA1, pA2, pA3, pB0, pB1, pB2, pB3;
        pA0.x = __expf(sA0.x); pA0.y = __expf(sA0.y); pA0.z = __expf(sA0.z); pA0.w = __expf(sA0.w);
        pA1.x = __expf(sA1.x); pA1.y = __expf(sA1.y); pA1.z = __expf(sA1.z); pA1.w = __expf(sA1.w);
        pA2.x = __expf(sA2.x); pA2.y = __expf(sA2.y); pA2.z = __expf(sA2.z); pA2.w = __expf(sA2.w);
        pA3.x = __expf(sA3.x); pA3.y = __expf(sA3.y); pA3.z = __expf(sA3.z); pA3.w = __expf(sA3.w);
        pB0.x = __expf(sB0.x); pB0.y = __expf(sB0.y); pB0.z = __expf(sB0.z); pB0.w = __expf(sB0.w);
        pB1.x = __expf(sB1.x); pB1.y = __expf(sB1.y); pB1.z = __expf(sB1.z); pB1.w = __expf(sB1.w);
        pB2.x = __expf(sB2.x); pB2.y = __expf(sB2.y); pB2.z = __expf(sB2.z); pB2.w = __expf(sB2.w);
        pB3.x = __expf(sB3.x); pB3.y = __expf(sB3.y); pB3.z = __expf(sB3.z); pB3.w = __expf(sB3.w);

        l0 += (pA0.x + pA0.y + pA0.z + pA0.w) + (pA1.x + pA1.y + pA1.z + pA1.w)
            + (pA2.x + pA2.y + pA2.z + pA2.w) + (pA3.x + pA3.y + pA3.z + pA3.w);
        l1 += (pB0.x + pB0.y + pB0.z + pB0.w) + (pB1.x + pB1.y + pB1.z + pB1.w)
            + (pB2.x + pB2.y + pB2.z + pB2.w) + (pB3.x + pB3.y + pB3.z + pB3.w);

        // ---- J: pack P half-0 (k-cols 0..63) -> pa0; issue vf1; PV-0 ----
        {
            f32x2 w;
            w.x = asf(packbf(pA0.x, pA0.y)); w.y = asf(packbf(pA0.z, pA0.w));
            *(f32x2*)&s_lds[rl0][cq * 2] = w;
            w.x = asf(packbf(pA1.x, pA1.y)); w.y = asf(packbf(pA1.z, pA1.w));
            *(f32x2*)&s_lds[rl0][16 + cq * 2] = w;
            w.x = asf(packbf(pB0.x, pB0.y)); w.y = asf(packbf(pB0.z, pB0.w));
            *(f32x2*)&s_lds[rl1][cq * 2] = w;
            w.x = asf(packbf(pB1.x, pB1.y)); w.y = asf(packbf(pB1.z, pB1.w));
            *(f32x2*)&s_lds[rl1][16 + cq * 2] = w;
        }
        bf16x8 pa[2];
#pragma unroll
        for (int kc = 0; kc < 2; ++kc) {
            f32x4 praw = *(const f32x4*)&s_lds[wave * 16 + ln][kc * 16 + lg * 4];
            pa[kc] = *(const bf16x8*)&praw;
        }
        bf16x8 vg[8];
#pragma unroll
        for (int nc = 0; nc < 4; ++nc)
#pragma unroll
            for (int kc = 0; kc < 2; ++kc)
                vg[nc * 2 + kc] = *(const bf16x8*)(vbase + (size_t)nc * 16 * SDIM + (t0 + 64 + kc * 32));
        __builtin_amdgcn_s_setprio(1);
#pragma unroll
        for (int nc = 0; nc < 4; ++nc)
#pragma unroll
            for (int kc = 0; kc < 2; ++kc)
                oacc[nc] = __builtin_amdgcn_mfma_f32_16x16x32_bf16(pa[kc], vf[nc * 2 + kc], oacc[nc], 0, 0, 0);
        __builtin_amdgcn_s_setprio(0);

        // ---- K: pack P half-1 (k-cols 64..127) -> pa1; PV-1 ----
        {
            f32x2 w;
            w.x = asf(packbf(pA2.x, pA2.y)); w.y = asf(packbf(pA2.z, pA2.w));
            *(f32x2*)&s_lds[rl0][cq * 2] = w;
            w.x = asf(packbf(pA3.x, pA3.y)); w.y = asf(packbf(pA3.z, pA3.w));
            *(f32x2*)&s_lds[rl0][16 + cq * 2] = w;
            w.x = asf(packbf(pB2.x, pB2.y)); w.y = asf(packbf(pB2.z, pB2.w));
            *(f32x2*)&s_lds[rl1][cq * 2] = w;
            w.x = asf(packbf(pB3.x, pB3.y)); w.y = asf(packbf(pB3.z, pB3.w));
            *(f32x2*)&s_lds[rl1][16 + cq * 2] = w;
        }
#pragma unroll
        for (int kc = 0; kc < 2; ++kc) {
            f32x4 praw = *(const f32x4*)&s_lds[wave * 16 + ln][kc * 16 + lg * 4];
            pa[kc] = *(const bf16x8*)&praw;
        }
        __builtin_amdgcn_s_setprio(1);
#pragma unroll
        for (int nc = 0; nc < 4; ++nc)
#pragma unroll
            for (int kc = 0; kc < 2; ++kc)
                oacc[nc] = __builtin_amdgcn_mfma_f32_16x16x32_bf16(pa[kc], vg[nc * 2 + kc], oacc[nc], 0, 0, 0);
        __builtin_amdgcn_s_setprio(0);
    }

    // ---- epilogue: reduce l over the 8 col-lanes ----
    l0 += __shfl_xor(l0, 1, 64);
    l0 += __shfl_xor(l0, 2, 64);
    l0 += __shfl_xor(l0, 4, 64);
    l1 += __shfl_xor(l1, 1, 64);
    l1 += __shfl_xor(l1, 2, 64);
    l1 += __shfl_xor(l1, 4, 64);
    const float li0 = 1.0f / l0;
    const float li1 = 1.0f / l1;

    // ---- O through LDS, two passes; full-line stores ----
    const size_t ob0 = ((size_t)bh * SDIM + qt * 64 + rl0) * DDIM + cq * 4;
    const size_t ob1 = ((size_t)bh * SDIM + qt * 64 + rl1) * DDIM + cq * 4;
#pragma unroll
    for (int r = 0; r < 4; ++r) {
        s_lds[wave * 16 + lg * 4 + r][ln]      = oacc[0][r];
        s_lds[wave * 16 + lg * 4 + r][16 + ln] = oacc[1][r];
    }
    f32x4 o00 = *(const f32x4*)&s_lds[rl0][cq * 4];
    f32x4 o10 = *(const f32x4*)&s_lds[rl1][cq * 4];
#pragma unroll
    for (int r = 0; r < 4; ++r) {
        s_lds[wave * 16 + lg * 4 + r][ln]      = oacc[2][r];
        s_lds[wave * 16 + lg * 4 + r][16 + ln] = oacc[3][r];
    }
    f32x4 o01 = *(const f32x4*)&s_lds[rl0][cq * 4];
    f32x4 o11 = *(const f32x4*)&s_lds[rl1][cq * 4];

    *(f32x4*)(out + ob0)      = o00 * li0;
    *(f32x4*)(out + ob0 + 32) = o01 * li0;
    *(f32x4*)(out + ob1)      = o10 * li1;
    *(f32x4*)(out + ob1 + 32) = o11 * li1;
}

extern "C" void kernel_launch(void* const* d_in, const int* in_sizes, int n_in,
                              void* d_out, int out_size, void* d_ws, size_t ws_size,
                              hipStream_t stream) {
    const float* q    = (const float*)d_in[0];
    const float* k    = (const float*)d_in[1];
    const float* v    = (const float*)d_in[2];
    const float* prev = (const float*)d_in[3];

    float* out    = (float*)d_out;
    float* scores = out + (size_t)NBH * SDIM * DDIM;   // outputs concatenated

    unsigned short* kT = (unsigned short*)d_ws;                 // [bh][2048][64] bf16
    unsigned short* vT = kT + (size_t)NBH * SDIM * DDIM;        // [bh][64][2048] bf16

    // k: [bh][64][2048] -> kT [bh][2048][64]
    transpose_cvt<<<dim3(SDIM / 64, 1, NBH), 256, 0, stream>>>(k, kT, DDIM, SDIM);
    // v: [bh][2048][64] -> vT [bh][64][2048]
    transpose_cvt<<<dim3(1, SDIM / 64, NBH), 256, 0, stream>>>(v, vT, SDIM, DDIM);

    attn_fused<<<dim3(SDIM / 64, NBH), 256, 0, stream>>>(q, prev, kT, vT, out, scores);
}

// Round 15
// 293.052 us; speedup vs baseline: 1.2960x; 1.2960x over previous
//
#include <hip/hip_runtime.h>

typedef __attribute__((ext_vector_type(8))) short bf16x8;
typedef __attribute__((ext_vector_type(4))) float f32x4;
typedef __attribute__((ext_vector_type(2))) float f32x2;
typedef __attribute__((ext_vector_type(4))) unsigned int u32x4;

#define SDIM 2048
#define DDIM 64
#define NBH  32
#define KBLK 128

__device__ __forceinline__ unsigned short f2bf(float f) {
    union { float f; unsigned int u; } x;
    x.f = f;
    unsigned int u = x.u;
    u += 0x7FFFu + ((u >> 16) & 1u);  // round-to-nearest-even
    return (unsigned short)(u >> 16);
}

__device__ __forceinline__ unsigned int packbf(float a, float b) {
    return (unsigned int)f2bf(a) | ((unsigned int)f2bf(b) << 16);
}

__device__ __forceinline__ float asf(unsigned int u) {
    union { unsigned int u; float f; } x; x.u = u; return x.f;
}

// transpose [bh][R][C] f32 -> [bh][C][R] bf16(ushort), 64x64 tiles via LDS
__global__ __launch_bounds__(256) void transpose_cvt(
    const float* __restrict__ in, unsigned short* __restrict__ out,
    int R, int C)
{
    __shared__ float tile[64][65];
    const int bh = blockIdx.z;
    const int ct = blockIdx.x * 64;
    const int rt = blockIdx.y * 64;
    const float* src = in + (size_t)bh * R * C;
    unsigned short* dst = out + (size_t)bh * R * C;
    const int r = threadIdx.x >> 2;   // 0..63
    const int p = threadIdx.x & 3;    // 0..3
    const float* sp = src + (size_t)(rt + r) * C + ct + p * 16;
#pragma unroll
    for (int j = 0; j < 4; ++j) {
        f32x4 a = *(const f32x4*)(sp + j * 4);
        tile[r][p*16 + j*4 + 0] = a.x;
        tile[r][p*16 + j*4 + 1] = a.y;
        tile[r][p*16 + j*4 + 2] = a.z;
        tile[r][p*16 + j*4 + 3] = a.w;
    }
    __syncthreads();
    u32x4 w0, w1;
    w0.x = packbf(tile[p*16+ 0][r], tile[p*16+ 1][r]);
    w0.y = packbf(tile[p*16+ 2][r], tile[p*16+ 3][r]);
    w0.z = packbf(tile[p*16+ 4][r], tile[p*16+ 5][r]);
    w0.w = packbf(tile[p*16+ 6][r], tile[p*16+ 7][r]);
    w1.x = packbf(tile[p*16+ 8][r], tile[p*16+ 9][r]);
    w1.y = packbf(tile[p*16+10][r], tile[p*16+11][r]);
    w1.z = packbf(tile[p*16+12][r], tile[p*16+13][r]);
    w1.w = packbf(tile[p*16+14][r], tile[p*16+15][r]);
    unsigned short* dp = dst + (size_t)(ct + r) * R + rt + p * 16;
    *(u32x4*)dp = w0;
    *(u32x4*)(dp + 8) = w1;
}

// Fused attention, no-max softmax, KBLK=128 with DRAM-page-friendly bursts:
// each scores/prev row moves 512B CONTIGUOUS per iteration, issued as 4
// back-to-back f32x4 per row. K tile (16KB) double-buffered in LDS via
// global_load_lds (no staging registers, no ds_write commit): per-lane
// PRE-SWIZZLED global source + linear LDS dest reproduces the XOR layout
// (involution), so QK^T reads stay bank-conflict-free. s_lds[64][36]
// two-pass intra-wave exchange (R13-proven). One __syncthreads per iter.
__global__ __launch_bounds__(256, 3) void attn_fused(
    const float* __restrict__ q, const float* __restrict__ prev,
    const unsigned short* __restrict__ kT, const unsigned short* __restrict__ vT,
    float* __restrict__ out, float* __restrict__ scores)
{
    const int bh   = blockIdx.y;
    const int qt   = blockIdx.x;          // 64-row Q tile index
    const int tid  = threadIdx.x;
    const int wave = tid >> 6;
    const int lane = tid & 63;
    const int ln   = lane & 15;           // 0..15
    const int lg   = lane >> 4;           // 0..3

    __shared__ float s_lds[64][36];            // S/P/O exchange (two-pass)
    __shared__ unsigned short ksmem[2][8192];  // K tile double buffer, 2x16KB

    // ---- Q fragments (A operand: row = ln, k(d) = kc*32 + lg*8 + j) ----
    const int qrow_frag = qt * 64 + wave * 16 + ln;
    bf16x8 qf[2];
    {
        const float* qp = q + ((size_t)bh * SDIM + qrow_frag) * DDIM + lg * 8;
#pragma unroll
        for (int kc = 0; kc < 2; ++kc) {
            f32x4 a = *(const f32x4*)(qp + kc * 32);
            f32x4 b = *(const f32x4*)(qp + kc * 32 + 4);
            bf16x8 f;
            f[0] = (short)f2bf(a.x); f[1] = (short)f2bf(a.y);
            f[2] = (short)f2bf(a.z); f[3] = (short)f2bf(a.w);
            f[4] = (short)f2bf(b.x); f[5] = (short)f2bf(b.y);
            f[6] = (short)f2bf(b.z); f[7] = (short)f2bf(b.w);
            qf[kc] = f;
        }
    }

    const unsigned short* kbh   = kT + (size_t)bh * SDIM * DDIM;
    const unsigned short* vbase = vT + ((size_t)bh * DDIM + ln) * SDIM + lg * 8;

    // ---- row-layout identity: 8 lanes per row, 2 row groups ----
    const int rsub = lane >> 3;           // 0..7
    const int cq   = lane & 7;            // col octet: floats cq*4..cq*4+3
    const int rl0  = wave * 16 + rsub;    // block-local rows
    const int rl1  = rl0 + 8;
    const size_t grow0 = ((size_t)bh * SDIM + qt * 64 + rl0) * SDIM + cq * 4;
    const size_t grow1 = ((size_t)bh * SDIM + qt * 64 + rl1) * SDIM + cq * 4;
    const float* prow0 = prev + grow0;
    const float* prow1 = prev + grow1;
    float* srow0 = scores + grow0;
    float* srow1 = scores + grow1;

    f32x4 oacc[4] = {};
    float l0 = 0.0f, l1 = 0.0f;

    // ---- K tile DMA: lane stages LDS chunk d = wave*256 + j*64 + lane,
    //      from global chunk g = d ^ ((d>>3)&7) (involution) ----
    auto stage_k = [&](int b, const unsigned short* ktile) {
#pragma unroll
        for (int j = 0; j < 4; ++j) {
            const int dbase = wave * 256 + j * 64;
            const int d = dbase + lane;
            const int g = d ^ ((d >> 3) & 7);
            __builtin_amdgcn_global_load_lds(
                (const __attribute__((address_space(1))) void*)(ktile + (size_t)g * 8),
                (__attribute__((address_space(3))) void*)&ksmem[b][dbase * 8],
                16, 0, 0);
        }
    };

    // ---- prologue: DMA K tile 0 into buf 0 ----
    stage_k(0, kbh);
    __syncthreads();

    for (int tt = 0; tt < SDIM / KBLK; ++tt) {
        const int t0  = tt * KBLK;
        const int buf = tt & 1;
        const bool more = tt < (SDIM / KBLK - 1);

        // ---- 1: prev burst — 512B contiguous per row, back-to-back ----
        f32x4 pf00 = __builtin_nontemporal_load((const f32x4*)(prow0 + t0));
        f32x4 pf01 = __builtin_nontemporal_load((const f32x4*)(prow0 + t0 + 32));
        f32x4 pf02 = __builtin_nontemporal_load((const f32x4*)(prow0 + t0 + 64));
        f32x4 pf03 = __builtin_nontemporal_load((const f32x4*)(prow0 + t0 + 96));
        f32x4 pf10 = __builtin_nontemporal_load((const f32x4*)(prow1 + t0));
        f32x4 pf11 = __builtin_nontemporal_load((const f32x4*)(prow1 + t0 + 32));
        f32x4 pf12 = __builtin_nontemporal_load((const f32x4*)(prow1 + t0 + 64));
        f32x4 pf13 = __builtin_nontemporal_load((const f32x4*)(prow1 + t0 + 96));

        // ---- 2: DMA next K tile into other buffer ----
        if (more) stage_k(buf ^ 1, kbh + (size_t)(t0 + KBLK) * DDIM);

        // ---- 3: S = Q @ K^T (8 col-blocks) from LDS-staged K ----
        f32x4 sacc[8] = {};
        __builtin_amdgcn_s_setprio(1);
#pragma unroll
        for (int nc = 0; nc < 8; ++nc) {
            const int trow = nc * 16 + ln;
            const int sw = trow & 7;
#pragma unroll
            for (int kc = 0; kc < 2; ++kc) {
                bf16x8 bf = *(const bf16x8*)&ksmem[buf][trow * 64 + ((kc * 4 + lg) ^ sw) * 8];
                sacc[nc] = __builtin_amdgcn_mfma_f32_16x16x32_bf16(qf[kc], bf, sacc[nc], 0, 0, 0);
            }
        }
        __builtin_amdgcn_s_setprio(0);

        // ---- 4: issue all V loads (consumed at PV below) ----
        bf16x8 vf[16];
#pragma unroll
        for (int nc = 0; nc < 4; ++nc)
#pragma unroll
            for (int kc2 = 0; kc2 < 4; ++kc2)
                vf[nc * 4 + kc2] = *(const bf16x8*)(vbase + (size_t)nc * 16 * SDIM + (t0 + kc2 * 32));

        // ---- 5: S exchange, four 32-col intra-wave passes ----
        f32x4 sA0, sA1, sA2, sA3, sB0, sB1, sB2, sB3;
#pragma unroll
        for (int r = 0; r < 4; ++r) {
            s_lds[wave * 16 + lg * 4 + r][ln]      = sacc[0][r];
            s_lds[wave * 16 + lg * 4 + r][16 + ln] = sacc[1][r];
        }
        sA0 = *(const f32x4*)&s_lds[rl0][cq * 4];
        sB0 = *(const f32x4*)&s_lds[rl1][cq * 4];
#pragma unroll
        for (int r = 0; r < 4; ++r) {
            s_lds[wave * 16 + lg * 4 + r][ln]      = sacc[2][r];
            s_lds[wave * 16 + lg * 4 + r][16 + ln] = sacc[3][r];
        }
        sA1 = *(const f32x4*)&s_lds[rl0][cq * 4];
        sB1 = *(const f32x4*)&s_lds[rl1][cq * 4];
#pragma unroll
        for (int r = 0; r < 4; ++r) {
            s_lds[wave * 16 + lg * 4 + r][ln]      = sacc[4][r];
            s_lds[wave * 16 + lg * 4 + r][16 + ln] = sacc[5][r];
        }
        sA2 = *(const f32x4*)&s_lds[rl0][cq * 4];
        sB2 = *(const f32x4*)&s_lds[rl1][cq * 4];
#pragma unroll
        for (int r = 0; r < 4; ++r) {
            s_lds[wave * 16 + lg * 4 + r][ln]      = sacc[6][r];
            s_lds[wave * 16 + lg * 4 + r][16 + ln] = sacc[7][r];
        }
        sA3 = *(const f32x4*)&s_lds[rl0][cq * 4];
        sB3 = *(const f32x4*)&s_lds[rl1][cq * 4];

        // ---- 6: scale + prev; 8 back-to-back nt stores (512B/row); exp ----
        sA0 = sA0 * 0.125f + pf00;
        sA1 = sA1 * 0.125f + pf01;
        sA2 = sA2 * 0.125f + pf02;
        sA3 = sA3 * 0.125f + pf03;
        sB0 = sB0 * 0.125f + pf10;
        sB1 = sB1 * 0.125f + pf11;
        sB2 = sB2 * 0.125f + pf12;
        sB3 = sB3 * 0.125f + pf13;
        __builtin_nontemporal_store(sA0, (f32x4*)(srow0 + t0));
        __builtin_nontemporal_store(sA1, (f32x4*)(srow0 + t0 + 32));
        __builtin_nontemporal_store(sA2, (f32x4*)(srow0 + t0 + 64));
        __builtin_nontemporal_store(sA3, (f32x4*)(srow0 + t0 + 96));
        __builtin_nontemporal_store(sB0, (f32x4*)(srow1 + t0));
        __builtin_nontemporal_store(sB1, (f32x4*)(srow1 + t0 + 32));
        __builtin_nontemporal_store(sB2, (f32x4*)(srow1 + t0 + 64));
        __builtin_nontemporal_store(sB3, (f32x4*)(srow1 + t0 + 96));

        f32x4 pA0, pA1, pA2, pA3, pB0, pB1, pB2, pB3;
        pA0.x = __expf(sA0.x); pA0.y = __expf(sA0.y); pA0.z = __expf(sA0.z); pA0.w = __expf(sA0.w);
        pA1.x = __expf(sA1.x); pA1.y = __expf(sA1.y); pA1.z = __expf(sA1.z); pA1.w = __expf(sA1.w);
        pA2.x = __expf(sA2.x); pA2.y = __expf(sA2.y); pA2.z = __expf(sA2.z); pA2.w = __expf(sA2.w);
        pA3.x = __expf(sA3.x); pA3.y = __expf(sA3.y); pA3.z = __expf(sA3.z); pA3.w = __expf(sA3.w);
        pB0.x = __expf(sB0.x); pB0.y = __expf(sB0.y); pB0.z = __expf(sB0.z); pB0.w = __expf(sB0.w);
        pB1.x = __expf(sB1.x); pB1.y = __expf(sB1.y); pB1.z = __expf(sB1.z); pB1.w = __expf(sB1.w);
        pB2.x = __expf(sB2.x); pB2.y = __expf(sB2.y); pB2.z = __expf(sB2.z); pB2.w = __expf(sB2.w);
        pB3.x = __expf(sB3.x); pB3.y = __expf(sB3.y); pB3.z = __expf(sB3.z); pB3.w = __expf(sB3.w);

        l0 += (pA0.x + pA0.y + pA0.z + pA0.w) + (pA1.x + pA1.y + pA1.z + pA1.w)
            + (pA2.x + pA2.y + pA2.z + pA2.w) + (pA3.x + pA3.y + pA3.z + pA3.w);
        l1 += (pB0.x + pB0.y + pB0.z + pB0.w) + (pB1.x + pB1.y + pB1.z + pB1.w)
            + (pB2.x + pB2.y + pB2.z + pB2.w) + (pB3.x + pB3.y + pB3.z + pB3.w);

        // ---- 7: pack P k-half 0 (cols t0..t0+63); PV-A ----
        bf16x8 pa[2];
        {
            f32x2 w;
            w.x = asf(packbf(pA0.x, pA0.y)); w.y = asf(packbf(pA0.z, pA0.w));
            *(f32x2*)&s_lds[rl0][cq * 2] = w;
            w.x = asf(packbf(pA1.x, pA1.y)); w.y = asf(packbf(pA1.z, pA1.w));
            *(f32x2*)&s_lds[rl0][16 + cq * 2] = w;
            w.x = asf(packbf(pB0.x, pB0.y)); w.y = asf(packbf(pB0.z, pB0.w));
            *(f32x2*)&s_lds[rl1][cq * 2] = w;
            w.x = asf(packbf(pB1.x, pB1.y)); w.y = asf(packbf(pB1.z, pB1.w));
            *(f32x2*)&s_lds[rl1][16 + cq * 2] = w;
        }
#pragma unroll
        for (int kc = 0; kc < 2; ++kc) {
            f32x4 praw = *(const f32x4*)&s_lds[wave * 16 + ln][kc * 16 + lg * 4];
            pa[kc] = *(const bf16x8*)&praw;
        }
        __builtin_amdgcn_s_setprio(1);
#pragma unroll
        for (int nc = 0; nc < 4; ++nc)
#pragma unroll
            for (int kc = 0; kc < 2; ++kc)
                oacc[nc] = __builtin_amdgcn_mfma_f32_16x16x32_bf16(pa[kc], vf[nc * 4 + kc], oacc[nc], 0, 0, 0);
        __builtin_amdgcn_s_setprio(0);

        // ---- 8: pack P k-half 1 (cols t0+64..t0+127); PV-B ----
        {
            f32x2 w;
            w.x = asf(packbf(pA2.x, pA2.y)); w.y = asf(packbf(pA2.z, pA2.w));
            *(f32x2*)&s_lds[rl0][cq * 2] = w;
            w.x = asf(packbf(pA3.x, pA3.y)); w.y = asf(packbf(pA3.z, pA3.w));
            *(f32x2*)&s_lds[rl0][16 + cq * 2] = w;
            w.x = asf(packbf(pB2.x, pB2.y)); w.y = asf(packbf(pB2.z, pB2.w));
            *(f32x2*)&s_lds[rl1][cq * 2] = w;
            w.x = asf(packbf(pB3.x, pB3.y)); w.y = asf(packbf(pB3.z, pB3.w));
            *(f32x2*)&s_lds[rl1][16 + cq * 2] = w;
        }
#pragma unroll
        for (int kc = 0; kc < 2; ++kc) {
            f32x4 praw = *(const f32x4*)&s_lds[wave * 16 + ln][kc * 16 + lg * 4];
            pa[kc] = *(const bf16x8*)&praw;
        }
        __builtin_amdgcn_s_setprio(1);
#pragma unroll
        for (int nc = 0; nc < 4; ++nc)
#pragma unroll
            for (int kc = 0; kc < 2; ++kc)
                oacc[nc] = __builtin_amdgcn_mfma_f32_16x16x32_bf16(pa[kc], vf[nc * 4 + 2 + kc], oacc[nc], 0, 0, 0);
        __builtin_amdgcn_s_setprio(0);

        // ---- 9: barrier (drains K-DMA for buf^1; s_lds passes done) ----
        __syncthreads();
    }

    // ---- epilogue: reduce l over the 8 col-lanes ----
    l0 += __shfl_xor(l0, 1, 64);
    l0 += __shfl_xor(l0, 2, 64);
    l0 += __shfl_xor(l0, 4, 64);
    l1 += __shfl_xor(l1, 1, 64);
    l1 += __shfl_xor(l1, 2, 64);
    l1 += __shfl_xor(l1, 4, 64);
    const float li0 = 1.0f / l0;
    const float li1 = 1.0f / l1;

    // ---- O through LDS, two passes; full-line stores ----
    const size_t ob0 = ((size_t)bh * SDIM + qt * 64 + rl0) * DDIM + cq * 4;
    const size_t ob1 = ((size_t)bh * SDIM + qt * 64 + rl1) * DDIM + cq * 4;
#pragma unroll
    for (int r = 0; r < 4; ++r) {
        s_lds[wave * 16 + lg * 4 + r][ln]      = oacc[0][r];
        s_lds[wave * 16 + lg * 4 + r][16 + ln] = oacc[1][r];
    }
    f32x4 o00 = *(const f32x4*)&s_lds[rl0][cq * 4];
    f32x4 o10 = *(const f32x4*)&s_lds[rl1][cq * 4];
#pragma unroll
    for (int r = 0; r < 4; ++r) {
        s_lds[wave * 16 + lg * 4 + r][ln]      = oacc[2][r];
        s_lds[wave * 16 + lg * 4 + r][16 + ln] = oacc[3][r];
    }
    f32x4 o01 = *(const f32x4*)&s_lds[rl0][cq * 4];
    f32x4 o11 = *(const f32x4*)&s_lds[rl1][cq * 4];

    *(f32x4*)(out + ob0)      = o00 * li0;
    *(f32x4*)(out + ob0 + 32) = o01 * li0;
    *(f32x4*)(out + ob1)      = o10 * li1;
    *(f32x4*)(out + ob1 + 32) = o11 * li1;
}

extern "C" void kernel_launch(void* const* d_in, const int* in_sizes, int n_in,
                              void* d_out, int out_size, void* d_ws, size_t ws_size,
                              hipStream_t stream) {
    const float* q    = (const float*)d_in[0];
    const float* k    = (const float*)d_in[1];
    const float* v    = (const float*)d_in[2];
    const float* prev = (const float*)d_in[3];

    float* out    = (float*)d_out;
    float* scores = out + (size_t)NBH * SDIM * DDIM;   // outputs concatenated

    unsigned short* kT = (unsigned short*)d_ws;                 // [bh][2048][64] bf16
    unsigned short* vT = kT + (size_t)NBH * SDIM * DDIM;        // [bh][64][2048] bf16

    // k: [bh][64][2048] -> kT [bh][2048][64]
    transpose_cvt<<<dim3(SDIM / 64, 1, NBH), 256, 0, stream>>>(k, kT, DDIM, SDIM);
    // v: [bh][2048][64] -> vT [bh][64][2048]
    transpose_cvt<<<dim3(1, SDIM / 64, NBH), 256, 0, stream>>>(v, vT, SDIM, DDIM);

    attn_fused<<<dim3(SDIM / 64, NBH), 256, 0, stream>>>(q, prev, kT, vT, out, scores);
}